// Round 4
// baseline (352.753 us; speedup 1.0000x reference)
//
#include <hip/hip_runtime.h>
#include <math.h>

#define Bn 16
#define Hh 512
#define Ww 512
#define TILE 16
#define NTHREADS 384

typedef __bf16 bfrag  __attribute__((ext_vector_type(8)));
typedef float  ffrag  __attribute__((ext_vector_type(16)));

__device__ __forceinline__ short f2bf(float f) {           // RNE fp32 -> bf16 bits
    unsigned u = __float_as_uint(f);
    unsigned r = u + 0x7FFFu + ((u >> 16) & 1u);
    return (short)(r >> 16);
}

// exact-GELU via A&S 7.1.26 erf approx (|eps| <= 1.5e-7), ~14 VALU inst
__device__ __forceinline__ float gelu_fast(float s) {
    float u  = s * 0.70710678118654752f;
    float au = fabsf(u);
    float t  = __builtin_amdgcn_rcpf(fmaf(0.3275911f, au, 1.0f));
    float p  = t * fmaf(t, fmaf(t, fmaf(t, fmaf(t, 1.061405429f, -1.453152027f),
                                        1.421413741f), -0.284496736f), 0.254829592f);
    float e  = __builtin_amdgcn_exp2f(-u * u * 1.44269504088896340f);
    float er = fmaf(-p, e, 1.0f);            // erf(|u|)
    er = copysignf(er, u);
    return 0.5f * s * (1.0f + er);
}

// ---- pre-pass: pack w2 and w1 into bf16 MFMA B-fragments in d_ws ----
// ws ints: [0, 2304)  B2: [tap][lane] 16B frags. B2[k=ci][n=co], lane n=l31, k=lh*8+j
//          [2304, 2816) B1: [step][lane] 16B frags. B1[k=ci*9+tap][n=co], k = s*16+lh*8+j
__global__ void pack_w(const float* __restrict__ w2, const float* __restrict__ w1,
                       int* __restrict__ ws) {
    const int lane = threadIdx.x;            // 64 threads
    const int l31  = lane & 31;
    const int lh   = lane >> 5;
    for (int tap = 0; tap < 9; ++tap) {
        int pk[4];
        #pragma unroll
        for (int jj = 0; jj < 4; ++jj) {
            float v0 = (l31 < 18) ? w2[(l31 * 16 + lh * 8 + 2 * jj    ) * 9 + tap] : 0.0f;
            float v1 = (l31 < 18) ? w2[(l31 * 16 + lh * 8 + 2 * jj + 1) * 9 + tap] : 0.0f;
            pk[jj] = ((int)(unsigned short)f2bf(v0)) | ((int)f2bf(v1) << 16);
        }
        ((int4*)ws)[tap * 64 + lane] = make_int4(pk[0], pk[1], pk[2], pk[3]);
    }
    for (int s = 0; s < 2; ++s) {
        int pk[4];
        #pragma unroll
        for (int jj = 0; jj < 4; ++jj) {
            int k0 = s * 16 + lh * 8 + 2 * jj;
            int k1 = k0 + 1;
            float v0 = (l31 < 16 && k0 < 27) ? w1[l31 * 27 + k0] : 0.0f;
            float v1 = (l31 < 16 && k1 < 27) ? w1[l31 * 27 + k1] : 0.0f;
            pk[jj] = ((int)(unsigned short)f2bf(v0)) | ((int)f2bf(v1) << 16);
        }
        ((int4*)ws)[576 + s * 64 + lane] = make_int4(pk[0], pk[1], pk[2], pk[3]);
    }
}

// LDS layout (bytes), regions alias across barriers:
//   s_in    float [3][20][20]   @ 0      (4800)   live P1-P2
//   s_patch bf16  [4][324][8]   @ 4800   (20736)  live P2-P3 (im2col A-matrix)
//   s_c1    float [324][17]     @ 0      (22032)  live P4-P5 (raw conv1 out; aliases s_in+patch)
//   s_feat  bf16  [2][324][8]   @ 22032  (10368)  live P5-P6 (gelu'd feat, conv2 A-matrix)
//   s_off   float [256][19]     @ 0      (19456)  live P6-P7 (offsets; aliases s_c1)
#define SMEM_BYTES 32416

__global__ __launch_bounds__(NTHREADS, 6) void residual_advection_fused(
    const float* __restrict__ pm25,   // (16,1,512,512)
    const float* __restrict__ wind,   // (16,2,512,512)
    const float* __restrict__ topo,   // (16,1,512,512)
    const float* __restrict__ b1,     // (16)
    const float* __restrict__ b2,     // (18)
    const float* __restrict__ wt,     // (9)
    const int*   __restrict__ wsB,    // packed B-fragments (B2 then B1)
    float* __restrict__ out)          // (16,1,512,512)
{
    __shared__ __align__(16) char smem[SMEM_BYTES];
    float (*s_in)[20][20] = (float (*)[20][20])smem;
    __bf16* s_patch = (__bf16*)(smem + 4800);
    float*  s_c1    = (float*)smem;
    __bf16* s_feat  = (__bf16*)(smem + 22032);
    float*  s_off   = (float*)smem;

    const int tid = threadIdx.x;
    const int bb  = blockIdx.z;
    const int ty0 = blockIdx.y * TILE;
    const int tx0 = blockIdx.x * TILE;
    const int HW  = Hh * Ww;

    const int lane = tid & 63;
    const int wv   = tid >> 6;
    const int l31  = lane & 31;
    const int lh   = lane >> 5;

    // ---- P1: stage input halo (zero outside image = conv1 zero padding) ----
    for (int idx = tid; idx < 3 * 20 * 20; idx += NTHREADS) {
        int c   = idx / 400;
        int rem = idx - c * 400;
        int ly  = rem / 20;
        int lx  = rem - ly * 20;
        int gy  = ty0 - 2 + ly;
        int gx  = tx0 - 2 + lx;
        float v = 0.0f;
        if (gy >= 0 && gy < Hh && gx >= 0 && gx < Ww) {
            if (c < 2) v = wind[(bb * 2 + c) * HW + gy * Ww + gx];
            else       v = topo[bb * HW + gy * Ww + gx];
        }
        s_in[c][ly][lx] = v;
    }
    __syncthreads();

    // ---- P2: im2col 3x3x3 patches -> bf16 A-matrix [k/8][pos][8] ----
    if (tid < 324) {
        int ly = tid / 18;
        int lx = tid - ly * 18;
        float patch[27];
        #pragma unroll
        for (int ci = 0; ci < 3; ++ci)
            #pragma unroll
            for (int ky = 0; ky < 3; ++ky)
                #pragma unroll
                for (int kx = 0; kx < 3; ++kx)
                    patch[ci * 9 + ky * 3 + kx] = s_in[ci][ly + ky][lx + kx];
        #pragma unroll
        for (int kh = 0; kh < 4; ++kh) {
            int pk[4];
            #pragma unroll
            for (int jj = 0; jj < 4; ++jj) {
                int k0 = kh * 8 + 2 * jj, k1 = k0 + 1;
                float v0 = (k0 < 27) ? patch[k0] : 0.0f;
                float v1 = (k1 < 27) ? patch[k1] : 0.0f;
                pk[jj] = ((int)(unsigned short)f2bf(v0)) | ((int)f2bf(v1) << 16);
            }
            *(int4*)&s_patch[(kh * 324 + tid) * 8] = make_int4(pk[0], pk[1], pk[2], pk[3]);
        }
    }
    __syncthreads();

    // ---- P3: conv1 via MFMA 32x32x16 bf16 (all 6 waves, 12 m-tiles of 32) ----
    ffrag c1a, c1b;
    #pragma unroll
    for (int r = 0; r < 16; ++r) { c1a[r] = 0.0f; c1b[r] = 0.0f; }
    {
        const bfrag* B1 = (const bfrag*)(wsB + 2304);
        const int m0 = (2 * wv) * 32 + l31;
        const int m1 = m0 + 32;
        #pragma unroll
        for (int s = 0; s < 2; ++s) {
            bfrag b  = B1[s * 64 + lane];
            bfrag a0 = *(const bfrag*)&s_patch[((2 * s + lh) * 324 + m0) * 8];
            bfrag a1 = *(const bfrag*)&s_patch[((2 * s + lh) * 324 + m1) * 8];
            c1a = __builtin_amdgcn_mfma_f32_32x32x16_bf16(a0, b, c1a, 0, 0, 0);
            c1b = __builtin_amdgcn_mfma_f32_32x32x16_bf16(a1, b, c1b, 0, 0, 0);
        }
    }
    __syncthreads();   // all A-reads done before s_c1 overwrites s_in/s_patch

    // ---- P4: raw conv1 D -> s_c1[pos][co] (stride 17) ----
    // C/D layout: col(co)=lane&31, row=(reg&3)+8*(reg>>2)+4*(lane>>5)
    if (l31 < 16) {
        #pragma unroll
        for (int reg = 0; reg < 16; ++reg) {
            int row = (reg & 3) + 8 * (reg >> 2) + 4 * lh;
            int m = (2 * wv) * 32 + row;
            if (m < 324)      s_c1[m * 17 + l31]        = c1a[reg];
            if (m + 32 < 324) s_c1[(m + 32) * 17 + l31] = c1b[reg];
        }
    }
    __syncthreads();

    // ---- P5: bias + GELU + zero-out-of-image -> bf16 s_feat (balanced, 384 thr) ----
    #pragma unroll
    for (int j = 0; j < 14; ++j) {
        int v = tid + NTHREADS * j;
        if (v < 324 * 16) {
            int p  = v >> 4;
            int co = v & 15;
            int ly = p / 18;
            int lx = p - ly * 18;
            int gy = ty0 - 1 + ly;
            int gx = tx0 - 1 + lx;
            float d = s_c1[p * 17 + co] + b1[co];
            float g = (gy >= 0 && gy < Hh && gx >= 0 && gx < Ww) ? gelu_fast(d) : 0.0f;
            ((short*)s_feat)[((co >> 3) * 324 + p) * 8 + (co & 7)] = f2bf(g);
        }
    }
    __syncthreads();

    // ---- P6: conv2 via MFMA 32x32x16 bf16 (waves 0-3; M=256, N=18, K=16x9) ----
    ffrag acc0, acc1;
    #pragma unroll
    for (int r = 0; r < 16; ++r) { acc0[r] = 0.0f; acc1[r] = 0.0f; }

    if (wv < 4) {
        const int m0   = wv * 64 + l31;
        const int m1   = m0 + 32;
        const int tyA0 = m0 >> 4, txA0 = m0 & 15;
        const int tyA1 = m1 >> 4, txA1 = m1 & 15;
        const bfrag* Bf = (const bfrag*)wsB;

        #pragma unroll
        for (int tap = 0; tap < 9; ++tap) {
            const int ky = tap / 3;
            const int kx = tap - ky * 3;
            bfrag b = Bf[tap * 64 + lane];
            const int p0 = (tyA0 + ky) * 18 + (txA0 + kx);
            const int p1 = (tyA1 + ky) * 18 + (txA1 + kx);
            bfrag a0 = *(const bfrag*)&s_feat[(lh * 324 + p0) * 8];
            bfrag a1 = *(const bfrag*)&s_feat[(lh * 324 + p1) * 8];
            acc0 = __builtin_amdgcn_mfma_f32_32x32x16_bf16(a0, b, acc0, 0, 0, 0);
            acc1 = __builtin_amdgcn_mfma_f32_32x32x16_bf16(a1, b, acc1, 0, 0, 0);
        }
    }
    // D2 (+bias) -> s_off[m][co] (stride 19). s_off aliases dead s_c1; disjoint from s_feat.
    if (wv < 4 && l31 < 18) {
        float bias = b2[l31];
        #pragma unroll
        for (int reg = 0; reg < 16; ++reg) {
            int row = (reg & 3) + 8 * (reg >> 2) + 4 * lh;
            s_off[(wv * 64 + row) * 19 + l31]      = acc0[reg] + bias;
            s_off[(wv * 64 + 32 + row) * 19 + l31] = acc1[reg] + bias;
        }
    }
    __syncthreads();

    // ---- P7: deformable 3x3 bilinear sampling of pm25, weighted by wt ----
    if (tid < 256) {
        const int ty = tid >> 4;
        const int tx = tid & 15;
        const int y  = ty0 + ty;
        const int x  = tx0 + tx;
        const float* img  = pm25 + bb * HW;
        const float* offp = s_off + tid * 19;

        float o = 0.0f;
        #pragma unroll
        for (int k = 0; k < 9; ++k) {
            float wk = wt[k];               // wave-uniform
            if (wk != 0.0f) {               // uniform branch: skips zero taps
                float dy = offp[2 * k];
                float dx = offp[2 * k + 1];
                float py = (float)y + (float)(k / 3 - 1) + dy;
                float px = (float)x + (float)(k % 3 - 1) + dx;
                float y0f = floorf(py), x0f = floorf(px);
                float wy = py - y0f, wx = px - x0f;
                int y0 = (int)y0f, x0 = (int)x0f;

                auto corner = [&](int yi, int xi) -> float {
                    bool valid = (yi >= 0) && (yi < Hh) && (xi >= 0) && (xi < Ww);
                    int yc = min(max(yi, 0), Hh - 1);
                    int xc = min(max(xi, 0), Ww - 1);
                    float v = img[yc * Ww + xc];
                    return valid ? v : 0.0f;
                };

                float v00 = corner(y0,     x0);
                float v01 = corner(y0,     x0 + 1);
                float v10 = corner(y0 + 1, x0);
                float v11 = corner(y0 + 1, x0 + 1);

                o += wk * ((1.0f - wy) * ((1.0f - wx) * v00 + wx * v01) +
                           wy          * ((1.0f - wx) * v10 + wx * v11));
            }
        }
        out[bb * HW + y * Ww + x] = o;
    }
}

extern "C" void kernel_launch(void* const* d_in, const int* in_sizes, int n_in,
                              void* d_out, int out_size, void* d_ws, size_t ws_size,
                              hipStream_t stream) {
    const float* pm25 = (const float*)d_in[0];
    const float* wind = (const float*)d_in[1];
    const float* topo = (const float*)d_in[2];
    const float* w1   = (const float*)d_in[3];
    const float* b1   = (const float*)d_in[4];
    const float* w2   = (const float*)d_in[5];
    const float* b2   = (const float*)d_in[6];
    const float* wt   = (const float*)d_in[7];
    float* o          = (float*)d_out;
    int*   wsB        = (int*)d_ws;   // (576+128)*16 = 11264 bytes used

    pack_w<<<dim3(1), dim3(64), 0, stream>>>(w2, w1, wsB);

    dim3 grid(Ww / TILE, Hh / TILE, Bn);
    residual_advection_fused<<<grid, dim3(NTHREADS), 0, stream>>>(
        pm25, wind, topo, b1, b2, wt, wsB, o);
}

// Round 5
// 300.230 us; speedup vs baseline: 1.1749x; 1.1749x over previous
//
#include <hip/hip_runtime.h>
#include <math.h>

#define Bn 16
#define Hh 512
#define Ww 512
#define TILE 32
#define NTHREADS 1024
#define HALO 34               // conv2 input halo (TILE+2)
#define INH 36                // conv1 input halo (TILE+4)
#define NPOS (HALO * HALO)    // 1156

typedef __bf16 bfrag  __attribute__((ext_vector_type(8)));
typedef float  ffrag  __attribute__((ext_vector_type(16)));

__device__ __forceinline__ short f2bf(float f) {           // RNE fp32 -> bf16 bits
    unsigned u = __float_as_uint(f);
    unsigned r = u + 0x7FFFu + ((u >> 16) & 1u);
    return (short)(r >> 16);
}

// gelu(x) ~= x * sigmoid(2*0.7978845608*(x + 0.044715 x^3)), ~8 VALU inst
__device__ __forceinline__ float gelu_fast(float x) {
    float z = x * x;
    float a = fmaf(z, 0.044715f, 1.0f);
    float m = x * 2.302208199f;            // x * 2*0.7978845608*log2(e)
    float u = m * a;
    float e = __builtin_amdgcn_exp2f(u);
    float r = __builtin_amdgcn_rcpf(e + 1.0f);
    return x - x * r;                      // x * e/(e+1)
}

// ---- pre-pass: pack w2 into bf16 MFMA B-fragments in d_ws ----
// layout: [tap][lane] -> 8 bf16 (16 B). B[k=ci][n=co]: lane n=l31, k=lh*8+j.
__global__ void pack_w2(const float* __restrict__ w2, int* __restrict__ ws) {
    const int lane = threadIdx.x;            // 64 threads
    const int l31  = lane & 31;
    const int lh   = lane >> 5;
    for (int tap = 0; tap < 9; ++tap) {
        int pk[4];
        #pragma unroll
        for (int jj = 0; jj < 4; ++jj) {
            float v0 = (l31 < 18) ? w2[(l31 * 16 + lh * 8 + 2 * jj    ) * 9 + tap] : 0.0f;
            float v1 = (l31 < 18) ? w2[(l31 * 16 + lh * 8 + 2 * jj + 1) * 9 + tap] : 0.0f;
            pk[jj] = ((int)(unsigned short)f2bf(v0)) | ((int)f2bf(v1) << 16);
        }
        ((int4*)ws)[tap * 64 + lane] = make_int4(pk[0], pk[1], pk[2], pk[3]);
    }
}

// LDS layout (bytes), regions alias across barriers:
//   s_in   float [3][36][36]  @ 0      (15552)  live P1-P2
//   s_feat bf16  [2][1156][8] @ 15552  (36992)  live P2-P3 (conv2 A-matrix)
//   s_off  float [1024][19]   @ 0      (77824)  live P4-P5 (aliases s_in+s_feat,
//                                               written only after all feat reads)
#define SMEM_BYTES 77824

__global__ __launch_bounds__(NTHREADS, 8) void residual_advection_fused(
    const float* __restrict__ pm25,   // (16,1,512,512)
    const float* __restrict__ wind,   // (16,2,512,512)
    const float* __restrict__ topo,   // (16,1,512,512)
    const float* __restrict__ w1,     // (16,3,3,3)
    const float* __restrict__ b1,     // (16)
    const float* __restrict__ b2,     // (18)
    const float* __restrict__ wt,     // (9)
    const int*   __restrict__ wsB,    // packed w2 B-fragments
    float* __restrict__ out)          // (16,1,512,512)
{
    __shared__ __align__(16) char smem[SMEM_BYTES];
    float (*s_in)[INH][INH] = (float (*)[INH][INH])smem;
    __bf16* s_feat = (__bf16*)(smem + 15552);   // [2][1156][8]
    float*  s_off  = (float*)smem;              // [1024][19]

    const int tid = threadIdx.x;
    const int bb  = blockIdx.z;
    const int ty0 = blockIdx.y * TILE;
    const int tx0 = blockIdx.x * TILE;
    const int HW  = Hh * Ww;

    const int lane = tid & 63;
    const int wv   = tid >> 6;       // 0..15
    const int l31  = lane & 31;
    const int lh   = lane >> 5;

    // ---- P1: stage input halo (zero outside image = conv1 zero padding) ----
    for (int idx = tid; idx < 3 * INH * INH; idx += NTHREADS) {
        int c   = idx / (INH * INH);
        int rem = idx - c * (INH * INH);
        int ly  = rem / INH;
        int lx  = rem - ly * INH;
        int gy  = ty0 - 2 + ly;
        int gx  = tx0 - 2 + lx;
        float v = 0.0f;
        if (gy >= 0 && gy < Hh && gx >= 0 && gx < Ww) {
            if (c < 2) v = wind[(bb * 2 + c) * HW + gy * Ww + gx];
            else       v = topo[bb * HW + gy * Ww + gx];
        }
        s_in[c][ly][lx] = v;
    }
    __syncthreads();

    // ---- P2: conv1 + fast GELU -> bf16 feat halo [khalf][pos][8ci] ----
    for (int pos = tid; pos < NPOS; pos += NTHREADS) {
        int ly = pos / HALO;
        int lx = pos - ly * HALO;
        int gy = ty0 - 1 + ly;
        int gx = tx0 - 1 + lx;
        float gv[16];
        if (gy < 0 || gy >= Hh || gx < 0 || gx >= Ww) {
            #pragma unroll
            for (int co = 0; co < 16; ++co) gv[co] = 0.0f;   // conv2 zero-padding
        } else {
            float f[27];
            #pragma unroll
            for (int ci = 0; ci < 3; ++ci)
                #pragma unroll
                for (int ky = 0; ky < 3; ++ky)
                    #pragma unroll
                    for (int kx = 0; kx < 3; ++kx)
                        f[ci * 9 + ky * 3 + kx] = s_in[ci][ly + ky][lx + kx];
            #pragma unroll
            for (int co = 0; co < 16; ++co) {
                float s = b1[co];
                #pragma unroll
                for (int j = 0; j < 27; ++j) s += f[j] * w1[co * 27 + j];
                gv[co] = gelu_fast(s);
            }
        }
        #pragma unroll
        for (int half = 0; half < 2; ++half) {
            int pk[4];
            #pragma unroll
            for (int jj = 0; jj < 4; ++jj) {
                pk[jj] = ((int)(unsigned short)f2bf(gv[half * 8 + 2 * jj]))
                       | ((int)f2bf(gv[half * 8 + 2 * jj + 1]) << 16);
            }
            *(int4*)&s_feat[(half * NPOS + pos) * 8] = make_int4(pk[0], pk[1], pk[2], pk[3]);
        }
    }
    __syncthreads();

    // ---- P3: conv2 via MFMA 32x32x16 bf16 (16 waves; M=1024 px, N=18, K=16x9) ----
    ffrag acc0, acc1;
    #pragma unroll
    for (int r = 0; r < 16; ++r) { acc0[r] = 0.0f; acc1[r] = 0.0f; }
    {
        const int m0   = wv * 64 + l31;
        const int m1   = m0 + 32;
        const int tyA0 = m0 >> 5, txA0 = m0 & 31;
        const int tyA1 = m1 >> 5, txA1 = m1 & 31;
        const bfrag* Bf = (const bfrag*)wsB;

        #pragma unroll
        for (int tap = 0; tap < 9; ++tap) {
            const int ky = tap / 3;
            const int kx = tap - ky * 3;
            bfrag b = Bf[tap * 64 + lane];
            const int p0 = (tyA0 + ky) * HALO + (txA0 + kx);
            const int p1 = (tyA1 + ky) * HALO + (txA1 + kx);
            bfrag a0 = *(const bfrag*)&s_feat[(lh * NPOS + p0) * 8];
            bfrag a1 = *(const bfrag*)&s_feat[(lh * NPOS + p1) * 8];
            acc0 = __builtin_amdgcn_mfma_f32_32x32x16_bf16(a0, b, acc0, 0, 0, 0);
            acc1 = __builtin_amdgcn_mfma_f32_32x32x16_bf16(a1, b, acc1, 0, 0, 0);
        }
    }
    __syncthreads();   // all feat reads done before s_off overwrites

    // ---- P4: write D (+bias) to s_off[m][co] (stride 19) ----
    // C/D layout: col(co)=lane&31, row=(reg&3)+8*(reg>>2)+4*(lane>>5)
    if (l31 < 18) {
        float bias = b2[l31];
        #pragma unroll
        for (int reg = 0; reg < 16; ++reg) {
            int row = (reg & 3) + 8 * (reg >> 2) + 4 * lh;
            s_off[(wv * 64 + row) * 19 + l31]      = acc0[reg] + bias;
            s_off[(wv * 64 + 32 + row) * 19 + l31] = acc1[reg] + bias;
        }
    }
    __syncthreads();

    // ---- P5: deformable 3x3 bilinear sampling of pm25, weighted by wt ----
    {
        const int ty = tid >> 5;
        const int tx = tid & 31;
        const int y  = ty0 + ty;
        const int x  = tx0 + tx;
        const float* img  = pm25 + bb * HW;
        const float* offp = s_off + tid * 19;

        float o = 0.0f;
        #pragma unroll
        for (int k = 0; k < 9; ++k) {
            float wk = wt[k];               // wave-uniform
            if (wk != 0.0f) {               // uniform branch: skips zero taps
                float dy = offp[2 * k];
                float dx = offp[2 * k + 1];
                float py = (float)y + (float)(k / 3 - 1) + dy;
                float px = (float)x + (float)(k % 3 - 1) + dx;
                float y0f = floorf(py), x0f = floorf(px);
                float wy = py - y0f, wx = px - x0f;
                int y0 = (int)y0f, x0 = (int)x0f;

                auto corner = [&](int yi, int xi) -> float {
                    bool valid = (yi >= 0) && (yi < Hh) && (xi >= 0) && (xi < Ww);
                    int yc = min(max(yi, 0), Hh - 1);
                    int xc = min(max(xi, 0), Ww - 1);
                    float v = img[yc * Ww + xc];
                    return valid ? v : 0.0f;
                };

                float v00 = corner(y0,     x0);
                float v01 = corner(y0,     x0 + 1);
                float v10 = corner(y0 + 1, x0);
                float v11 = corner(y0 + 1, x0 + 1);

                o += wk * ((1.0f - wy) * ((1.0f - wx) * v00 + wx * v01) +
                           wy          * ((1.0f - wx) * v10 + wx * v11));
            }
        }
        out[bb * HW + y * Ww + x] = o;
    }
}

extern "C" void kernel_launch(void* const* d_in, const int* in_sizes, int n_in,
                              void* d_out, int out_size, void* d_ws, size_t ws_size,
                              hipStream_t stream) {
    const float* pm25 = (const float*)d_in[0];
    const float* wind = (const float*)d_in[1];
    const float* topo = (const float*)d_in[2];
    const float* w1   = (const float*)d_in[3];
    const float* b1   = (const float*)d_in[4];
    const float* w2   = (const float*)d_in[5];
    const float* b2   = (const float*)d_in[6];
    const float* wt   = (const float*)d_in[7];
    float* o          = (float*)d_out;
    int*   wsB        = (int*)d_ws;   // 9*64*16 = 9216 bytes

    pack_w2<<<dim3(1), dim3(64), 0, stream>>>(w2, wsB);

    dim3 grid(Ww / TILE, Hh / TILE, Bn);
    residual_advection_fused<<<grid, dim3(NTHREADS), 0, stream>>>(
        pm25, wind, topo, w1, b1, b2, wt, wsB, o);
}

// Round 6
// 232.070 us; speedup vs baseline: 1.5200x; 1.2937x over previous
//
#include <hip/hip_runtime.h>
#include <math.h>

#define Bn 16
#define Hh 512
#define Ww 512
#define TILE 32
#define NTHREADS 1024
#define HALO 34               // conv2 input halo (TILE+2)
#define INH 36                // conv1 input halo (TILE+4)
#define NPOS (HALO * HALO)    // 1156

typedef __bf16 bfrag  __attribute__((ext_vector_type(8)));
typedef float  ffrag  __attribute__((ext_vector_type(16)));

__device__ __forceinline__ short f2bf(float f) {           // RNE fp32 -> bf16 bits
    unsigned u = __float_as_uint(f);
    unsigned r = u + 0x7FFFu + ((u >> 16) & 1u);
    return (short)(r >> 16);
}

// gelu(x) ~= x * sigmoid(2*0.7978845608*(x + 0.044715 x^3)), ~8 VALU inst
__device__ __forceinline__ float gelu_fast(float x) {
    float z = x * x;
    float a = fmaf(z, 0.044715f, 1.0f);
    float m = x * 2.302208199f;            // x * 2*0.7978845608*log2(e)
    float u = m * a;
    float e = __builtin_amdgcn_exp2f(u);
    float r = __builtin_amdgcn_rcpf(e + 1.0f);
    return x - x * r;                      // x * e/(e+1)
}

// ---- pre-pass: pack w2 B-fragments + transpose w1 into d_ws ----
// ws ints  [0, 2304)    : B2 frags [tap][lane] 16B. B2[k=ci][n=co], lane n=l31, k=lh*8+j
// ws floats[2304, 2736) : w1t[j][co] = w1[co*27+j]  (432 floats)
__global__ void pack_w(const float* __restrict__ w2, const float* __restrict__ w1,
                       int* __restrict__ ws) {
    const int lane = threadIdx.x;            // 64 threads
    const int l31  = lane & 31;
    const int lh   = lane >> 5;
    for (int tap = 0; tap < 9; ++tap) {
        int pk[4];
        #pragma unroll
        for (int jj = 0; jj < 4; ++jj) {
            float v0 = (l31 < 18) ? w2[(l31 * 16 + lh * 8 + 2 * jj    ) * 9 + tap] : 0.0f;
            float v1 = (l31 < 18) ? w2[(l31 * 16 + lh * 8 + 2 * jj + 1) * 9 + tap] : 0.0f;
            pk[jj] = ((int)(unsigned short)f2bf(v0)) | ((int)f2bf(v1) << 16);
        }
        ((int4*)ws)[tap * 64 + lane] = make_int4(pk[0], pk[1], pk[2], pk[3]);
    }
    float* w1t = (float*)(ws + 2304);
    for (int idx = lane; idx < 432; idx += 64) {
        int co = idx & 15;
        int j  = idx >> 4;
        w1t[idx] = w1[co * 27 + j];
    }
}

// LDS layout (bytes), regions alias across barriers:
//   s_in   float [3][36][36]  @ 0      (15552)  live P1-P2
//   s_feat bf16  [2][1156][8] @ 15552  (36992)  live P2-P3 (conv2 A-matrix)
//   s_off  float [1024][19]   @ 0      (77824)  live P4-P5 (aliases s_in+s_feat,
//                                               written only after all feat reads)
#define SMEM_BYTES 77824

__global__ __launch_bounds__(NTHREADS, 8) void residual_advection_fused(
    const float* __restrict__ pm25,   // (16,1,512,512)
    const float* __restrict__ wind,   // (16,2,512,512)
    const float* __restrict__ topo,   // (16,1,512,512)
    const float* __restrict__ b1,     // (16)
    const float* __restrict__ b2,     // (18)
    const float* __restrict__ wt,     // (9)
    const int*   __restrict__ wsB,    // packed w2 B-fragments + w1t
    float* __restrict__ out)          // (16,1,512,512)
{
    __shared__ __align__(16) char smem[SMEM_BYTES];
    float (*s_in)[INH][INH] = (float (*)[INH][INH])smem;
    __bf16* s_feat = (__bf16*)(smem + 15552);   // [2][1156][8]
    float*  s_off  = (float*)smem;              // [1024][19]

    const int tid = threadIdx.x;
    const int bb  = blockIdx.z;
    const int ty0 = blockIdx.y * TILE;
    const int tx0 = blockIdx.x * TILE;
    const int HW  = Hh * Ww;

    const int lane = tid & 63;
    const int wv   = tid >> 6;       // 0..15
    const int l31  = lane & 31;
    const int lh   = lane >> 5;

    const float* w1t = (const float*)(wsB + 2304);

    // ---- P1: stage input halo (zero outside image = conv1 zero padding) ----
    for (int idx = tid; idx < 3 * INH * INH; idx += NTHREADS) {
        int c   = idx / (INH * INH);
        int rem = idx - c * (INH * INH);
        int ly  = rem / INH;
        int lx  = rem - ly * INH;
        int gy  = ty0 - 2 + ly;
        int gx  = tx0 - 2 + lx;
        float v = 0.0f;
        if (gy >= 0 && gy < Hh && gx >= 0 && gx < Ww) {
            if (c < 2) v = wind[(bb * 2 + c) * HW + gy * Ww + gx];
            else       v = topo[bb * HW + gy * Ww + gx];
        }
        s_in[c][ly][lx] = v;
    }
    __syncthreads();

    // ---- P2: conv1 (j-outer / co-inner, SGPR weights) + GELU -> bf16 feat ----
    for (int pos = tid; pos < NPOS; pos += NTHREADS) {
        int ly = pos / HALO;
        int lx = pos - ly * HALO;
        int gy = ty0 - 1 + ly;
        int gx = tx0 - 1 + lx;
        float gv[16];
        if (gy >= 0 && gy < Hh && gx >= 0 && gx < Ww) {
            #pragma unroll
            for (int co = 0; co < 16; ++co) gv[co] = b1[co];
            #pragma unroll
            for (int c = 0; c < 3; ++c)
                #pragma unroll
                for (int ky = 0; ky < 3; ++ky)
                    #pragma unroll
                    for (int kx = 0; kx < 3; ++kx) {
                        float f = s_in[c][ly + ky][lx + kx];   // 1 ds_read, imm offset
                        const float* wj = w1t + (c * 9 + ky * 3 + kx) * 16;
                        #pragma unroll
                        for (int co = 0; co < 16; ++co)
                            gv[co] = fmaf(f, wj[co], gv[co]);  // v_fmac with SGPR weight
                    }
            #pragma unroll
            for (int co = 0; co < 16; ++co) gv[co] = gelu_fast(gv[co]);
        } else {
            #pragma unroll
            for (int co = 0; co < 16; ++co) gv[co] = 0.0f;     // conv2 zero-padding
        }
        #pragma unroll
        for (int half = 0; half < 2; ++half) {
            int pk[4];
            #pragma unroll
            for (int jj = 0; jj < 4; ++jj) {
                pk[jj] = ((int)(unsigned short)f2bf(gv[half * 8 + 2 * jj]))
                       | ((int)f2bf(gv[half * 8 + 2 * jj + 1]) << 16);
            }
            *(int4*)&s_feat[(half * NPOS + pos) * 8] = make_int4(pk[0], pk[1], pk[2], pk[3]);
        }
    }
    __syncthreads();

    // ---- P3: conv2 via MFMA 32x32x16 bf16 (16 waves; M=1024 px, N=18, K=16x9) ----
    ffrag acc0, acc1;
    #pragma unroll
    for (int r = 0; r < 16; ++r) { acc0[r] = 0.0f; acc1[r] = 0.0f; }
    {
        const int m0   = wv * 64 + l31;
        const int m1   = m0 + 32;
        const int tyA0 = m0 >> 5, txA0 = m0 & 31;
        const int tyA1 = m1 >> 5, txA1 = m1 & 31;
        const bfrag* Bf = (const bfrag*)wsB;

        #pragma unroll
        for (int tap = 0; tap < 9; ++tap) {
            const int ky = tap / 3;
            const int kx = tap - ky * 3;
            bfrag b = Bf[tap * 64 + lane];
            const int p0 = (tyA0 + ky) * HALO + (txA0 + kx);
            const int p1 = (tyA1 + ky) * HALO + (txA1 + kx);
            bfrag a0 = *(const bfrag*)&s_feat[(lh * NPOS + p0) * 8];
            bfrag a1 = *(const bfrag*)&s_feat[(lh * NPOS + p1) * 8];
            acc0 = __builtin_amdgcn_mfma_f32_32x32x16_bf16(a0, b, acc0, 0, 0, 0);
            acc1 = __builtin_amdgcn_mfma_f32_32x32x16_bf16(a1, b, acc1, 0, 0, 0);
        }
    }
    __syncthreads();   // all feat reads done before s_off overwrites

    // ---- P4: write D (+bias) to s_off[m][co] (stride 19) ----
    // C/D layout: col(co)=lane&31, row=(reg&3)+8*(reg>>2)+4*(lane>>5)
    if (l31 < 18) {
        float bias = b2[l31];
        #pragma unroll
        for (int reg = 0; reg < 16; ++reg) {
            int row = (reg & 3) + 8 * (reg >> 2) + 4 * lh;
            s_off[(wv * 64 + row) * 19 + l31]      = acc0[reg] + bias;
            s_off[(wv * 64 + 32 + row) * 19 + l31] = acc1[reg] + bias;
        }
    }
    __syncthreads();

    // ---- P5: deformable 3x3 bilinear sampling of pm25, weighted by wt ----
    {
        const int ty = tid >> 5;
        const int tx = tid & 31;
        const int y  = ty0 + ty;
        const int x  = tx0 + tx;
        const float* img  = pm25 + bb * HW;
        const float* offp = s_off + tid * 19;

        float o = 0.0f;
        #pragma unroll
        for (int k = 0; k < 9; ++k) {
            float wk = wt[k];               // wave-uniform
            if (wk != 0.0f) {               // uniform branch: skips zero taps
                float dy = offp[2 * k];
                float dx = offp[2 * k + 1];
                float py = (float)y + (float)(k / 3 - 1) + dy;
                float px = (float)x + (float)(k % 3 - 1) + dx;
                float y0f = floorf(py), x0f = floorf(px);
                float wy = py - y0f, wx = px - x0f;
                int y0 = (int)y0f, x0 = (int)x0f;

                auto corner = [&](int yi, int xi) -> float {
                    bool valid = (yi >= 0) && (yi < Hh) && (xi >= 0) && (xi < Ww);
                    int yc = min(max(yi, 0), Hh - 1);
                    int xc = min(max(xi, 0), Ww - 1);
                    float v = img[yc * Ww + xc];
                    return valid ? v : 0.0f;
                };

                float v00 = corner(y0,     x0);
                float v01 = corner(y0,     x0 + 1);
                float v10 = corner(y0 + 1, x0);
                float v11 = corner(y0 + 1, x0 + 1);

                o += wk * ((1.0f - wy) * ((1.0f - wx) * v00 + wx * v01) +
                           wy          * ((1.0f - wx) * v10 + wx * v11));
            }
        }
        out[bb * HW + y * Ww + x] = o;
    }
}

extern "C" void kernel_launch(void* const* d_in, const int* in_sizes, int n_in,
                              void* d_out, int out_size, void* d_ws, size_t ws_size,
                              hipStream_t stream) {
    const float* pm25 = (const float*)d_in[0];
    const float* wind = (const float*)d_in[1];
    const float* topo = (const float*)d_in[2];
    const float* w1   = (const float*)d_in[3];
    const float* b1   = (const float*)d_in[4];
    const float* w2   = (const float*)d_in[5];
    const float* b2   = (const float*)d_in[6];
    const float* wt   = (const float*)d_in[7];
    float* o          = (float*)d_out;
    int*   wsB        = (int*)d_ws;   // 9216 B frags + 1728 B w1t = 10944 B

    pack_w<<<dim3(1), dim3(64), 0, stream>>>(w2, w1, wsB);

    dim3 grid(Ww / TILE, Hh / TILE, Bn);
    residual_advection_fused<<<grid, dim3(NTHREADS), 0, stream>>>(
        pm25, wind, topo, b1, b2, wt, wsB, o);
}